// Round 8
// baseline (591.553 us; speedup 1.0000x reference)
//
#include <hip/hip_runtime.h>
#include <hip/hip_bf16.h>
#include <hip/hip_fp8.h>

#define BB 32768
#define AA 64
#define HH 1024
#define DD 256
#define KK 4096

typedef __attribute__((ext_vector_type(4))) float f32x4;
typedef __attribute__((ext_vector_type(4))) int v4i;
typedef __attribute__((ext_vector_type(8))) int v8i;
typedef unsigned long long u64;
typedef unsigned char u8;
typedef unsigned int u32;

__device__ __forceinline__ u8 f2f8(float x) { __hip_fp8_e4m3 v(x); return (u8)v.__x; }
__device__ __forceinline__ float f8tof(u8 b) { __hip_fp8_e4m3 t; t.__x = (__hip_fp8_storage_t)b; return (float)t; }
__device__ __forceinline__ unsigned f2ord(float f) {
    unsigned u = __float_as_uint(f);
    return (u & 0x80000000u) ? ~u : (u | 0x80000000u);
}

// ---------------------------------------------------------------------------
// MX fragment-major layout for operand X[rows x K], K multiple of 128:
//   super-fragment (R = row/16, S = k/128) = 2048 B at (R*KST + S)*2048,
//   lane = (row%16) | ((k%128)/32)<<4;  within lane, 32 contiguous bytes:
//   byte index = (k%32) stored as half h = (k%32)/16 at  h*1024 + lane*16.
// A and B use the IDENTICAL (lane,byte)->k map, so the MFMA dot product is
// correct for ANY internal HW k-permutation (permutation cancels).
// Scales: action x8, weights x64, activations x16, codebook & q x1024.
// ---------------------------------------------------------------------------

__global__ void prep_kernel(const float* __restrict__ action,
                            const float* __restrict__ enc_w1,
                            const float* __restrict__ enc_w2,
                            const float* __restrict__ mu_w,
                            const float* __restrict__ codebook,
                            const float* __restrict__ dec_w1,
                            const float* __restrict__ dec_w2,
                            const float* __restrict__ dec_w3,
                            u8* __restrict__ af8, u8* __restrict__ ew1t,
                            u8* __restrict__ ew2t, u8* __restrict__ muwt,
                            u8* __restrict__ cbf8, u8* __restrict__ dw1t,
                            u8* __restrict__ dw2t, u8* __restrict__ dw3t,
                            float* __restrict__ cnorm)
{
    int blk = blockIdx.x;
    const int t = threadIdx.x;

// u64-group index g: frag = g>>8; within frag: lane = (g&255)>>2, w = g&3.
// k = S*128 + (lane>>4)*32 + w*8 + j ;  row n = R*16 + (lane&15).
#define PACK_SECTION(NBLK, KST_, DST, READER)                                  \
    if (blk < (NBLK)) {                                                        \
        _Pragma("unroll")                                                      \
        for (int i = 0; i < 4; i++) {                                          \
            int g = blk * 1024 + i * 256 + t;                                  \
            int gl = g & 255;                                                  \
            int lane = gl >> 2, w = gl & 3;                                    \
            int F = g >> 8;                                                    \
            int S = F % (KST_);                                                \
            int R = F / (KST_);                                                \
            int n = R * 16 + (lane & 15);                                      \
            int k0 = S * 128 + ((lane >> 4) << 5) + (w << 3);                  \
            u64 wv = 0;                                                        \
            _Pragma("unroll")                                                  \
            for (int j = 0; j < 8; j++) {                                      \
                int k = k0 + j;                                                \
                float val = (READER);                                          \
                wv |= (u64)f2f8(val) << (8 * j);                               \
            }                                                                  \
            ((u64*)(DST))[g] = wv;                                             \
        }                                                                      \
        return;                                                                \
    }                                                                          \
    blk -= (NBLK);

    // action [32768x64] -> af8 [rows=32768, K=128 pad], x8     (512 blocks)
    PACK_SECTION(512, 1, af8, (k < AA ? action[n * AA + k] * 8.f : 0.f))
    // enc_w1 (64,1024) -> ew1t [1024, K=128 pad], x64          (16)
    PACK_SECTION(16, 1, ew1t, (k < AA ? enc_w1[k * HH + n] * 64.f : 0.f))
    // enc_w2 (1024,1024) -> ew2t [1024, K=1024], x64           (128)
    PACK_SECTION(128, 8, ew2t, (enc_w2[k * HH + n] * 64.f))
    // mu_w (1024,256) -> muwt [256, K=1024], x64               (32)
    PACK_SECTION(32, 8, muwt, (mu_w[k * DD + n] * 64.f))
    // codebook [4096x256] -> cbf8 [4096, K=256], x1024         (128)
    PACK_SECTION(128, 2, cbf8, (codebook[n * DD + k] * 1024.f))
    // dec_w1 (256,1024) -> dw1t [1024, K=256], x64             (32)
    PACK_SECTION(32, 2, dw1t, (dec_w1[k * HH + n] * 64.f))
    // dec_w2 (1024,1024) -> dw2t [1024, K=1024], x64           (128)
    PACK_SECTION(128, 8, dw2t, (dec_w2[k * HH + n] * 64.f))
    // dec_w3 (1024,64) -> dw3t [rows=128 pad, K=1024], x64     (16)
    PACK_SECTION(16, 8, dw3t, (n < AA ? dec_w3[k * AA + n] * 64.f : 0.f))
#undef PACK_SECTION

    {   // cnorm: 4 rows/block, wave per row, fp32 exact        (1024)
        int wave = t >> 6, lane = t & 63;
        int row = blk * 4 + wave;
        const float4* cr = (const float4*)(codebook + (long)row * DD);
        float4 v = cr[lane];
        float s = v.x * v.x + v.y * v.y + v.z * v.z + v.w * v.w;
#pragma unroll
        for (int off = 32; off; off >>= 1) s += __shfl_down(s, off);
        if (lane == 0) cnorm[row] = s;
    }
}

// ---------------------------------------------------------------------------
// MX-fp8 GEMM: C = (A[M,K] * Bt[N,K]^T) * ds.  128x128 tile, 4 waves (2x2 of
// 64x64), mfma_scale_f32_16x16x128_f8f6f4 (uniform E8M0 scale = 1.0).
// BK=128: per iter 8 glds (width 16) + barrier + 16 conflict-free
// ds_read_b128 + 16 MX-MFMA + barrier.  LDS 32 KB, 4 blocks/CU.
// EPI 0/1: (relu)(v*ds+bias)*os -> C fragment-major via arena transpose
// EPI 2:   VQ argmin (cnorm - 2v*ds -> u64 atomicMin keys)
// EPI 3:   tanh(v*ds+bias), SSE vs fp32 action -> partials[64+..]
// ---------------------------------------------------------------------------
template <int N, int K, int EPI>
__global__ __launch_bounds__(256, 4) void gemm_mx(
    const u8* __restrict__ A, const u8* __restrict__ Bt,
    const float* __restrict__ bias, u8* __restrict__ C,
    float ds, float os,
    const float* __restrict__ cnorm, u64* __restrict__ keys,
    const float* __restrict__ actionf, float* __restrict__ partials)
{
    constexpr int KST = K / 128;
    constexpr int KSTo = N / 128;
    __shared__ __align__(16) u8 arena[32768];
    u8* sA = arena;
    u8* sB = arena + 16384;
    const int t = threadIdx.x;
    const int wave = t >> 6, lane = t & 63;
    const int quad = lane >> 4, l16 = lane & 15;
    const int wm = (wave >> 1) << 6, wn = (wave & 1) << 6;
    const int tRm = blockIdx.y << 3;          // tile_m / 16
    const int tRn = blockIdx.x << 3;          // tile_n / 16
    const int tile_m = blockIdx.y << 7;
    const int tile_n = blockIdx.x << 7;

    f32x4 acc[4][4];
#pragma unroll
    for (int i = 0; i < 4; i++)
#pragma unroll
        for (int j = 0; j < 4; j++) acc[i][j] = (f32x4){0.f, 0.f, 0.f, 0.f};

    const int slane = lane * 32;              // per-lane global staging offset

    for (int s = 0; s < KST; s++) {
#pragma unroll
        for (int p = 0; p < 2; p++) {
            int f = wave * 2 + p;
            const u8* srcA = A + ((long)(tRm + f) * KST + s) * 2048 + slane;
            const u8* srcB = Bt + ((long)(tRn + f) * KST + s) * 2048 + slane;
            u8* dA = sA + f * 2048;           // wave-uniform LDS base (+lane*16 by HW)
            u8* dB = sB + f * 2048;
            __builtin_amdgcn_global_load_lds((const __attribute__((address_space(1))) u32*)srcA,
                                             (__attribute__((address_space(3))) u32*)dA, 16, 0, 0);
            __builtin_amdgcn_global_load_lds((const __attribute__((address_space(1))) u32*)(srcA + 16),
                                             (__attribute__((address_space(3))) u32*)(dA + 1024), 16, 0, 0);
            __builtin_amdgcn_global_load_lds((const __attribute__((address_space(1))) u32*)srcB,
                                             (__attribute__((address_space(3))) u32*)dB, 16, 0, 0);
            __builtin_amdgcn_global_load_lds((const __attribute__((address_space(1))) u32*)(srcB + 16),
                                             (__attribute__((address_space(3))) u32*)(dB + 1024), 16, 0, 0);
        }
        __syncthreads();
        v8i a[4];
#pragma unroll
        for (int i = 0; i < 4; i++) {
            const u8* p0 = sA + ((wm >> 4) + i) * 2048 + lane * 16;
            v4i lo = *(const v4i*)p0;
            v4i hi = *(const v4i*)(p0 + 1024);
            a[i] = (v8i){lo[0], lo[1], lo[2], lo[3], hi[0], hi[1], hi[2], hi[3]};
        }
#pragma unroll
        for (int j = 0; j < 4; j++) {
            const u8* p0 = sB + ((wn >> 4) + j) * 2048 + lane * 16;
            v4i lo = *(const v4i*)p0;
            v4i hi = *(const v4i*)(p0 + 1024);
            v8i b = (v8i){lo[0], lo[1], lo[2], lo[3], hi[0], hi[1], hi[2], hi[3]};
#pragma unroll
            for (int i = 0; i < 4; i++)
                acc[i][j] = __builtin_amdgcn_mfma_scale_f32_16x16x128_f8f6f4(
                    a[i], b, acc[i][j], 0, 0, 0, 0x7F7F7F7F, 0, 0x7F7F7F7F);
        }
        __syncthreads();
    }

    // C/D layout: col = lane&15, row = quad*4 + reg
    if (EPI == 0 || EPI == 1) {
        // 1) fp8 tile into arena (stride 136 B; 8-aligned u64 readback)
#pragma unroll
        for (int i = 0; i < 4; i++) {
            int row = wm + i * 16 + (quad << 2);
#pragma unroll
            for (int j = 0; j < 4; j++) {
                int col = wn + j * 16 + l16;
                float bv = bias[tile_n + col];
#pragma unroll
                for (int r = 0; r < 4; r++) {
                    float v = __builtin_fmaf(acc[i][j][r], ds, bv);
                    if (EPI == 0) v = fmaxf(v, 0.f);
                    arena[(row + r) * 136 + col] = f2f8(v * os);
                }
            }
        }
        __syncthreads();
        // 2) read back in MX-fragment order, coalesced 32 B/lane stores
#pragma unroll
        for (int p = 0; p < 2; p++) {
            int f = wave * 2 + p;
            int a0 = (f * 16 + l16) * 136 + ((lane >> 4) << 5);
            u64 q0 = *(const u64*)&arena[a0];
            u64 q1 = *(const u64*)&arena[a0 + 8];
            u64 q2 = *(const u64*)&arena[a0 + 16];
            u64 q3 = *(const u64*)&arena[a0 + 24];
            u64* dst = (u64*)(C + ((long)(tRm + f) * KSTo + blockIdx.x) * 2048 + lane * 32);
            dst[0] = q0; dst[1] = q1; dst[2] = q2; dst[3] = q3;
        }
    } else if (EPI == 2) {
#pragma unroll
        for (int i = 0; i < 4; i++) {
#pragma unroll
            for (int r = 0; r < 4; r++) {
                float best = 3.4e38f; int bi = 0;
#pragma unroll
                for (int j = 0; j < 4; j++) {
                    int col = tile_n + wn + j * 16 + l16;
                    float v = __builtin_fmaf(-2.f * ds, acc[i][j][r], cnorm[col]);
                    if (v < best || (v == best && col < bi)) { best = v; bi = col; }
                }
#pragma unroll
                for (int off = 1; off < 16; off <<= 1) {
                    float ov = __shfl_xor(best, off);
                    int   oi = __shfl_xor(bi, off);
                    if (ov < best || (ov == best && oi < bi)) { best = ov; bi = oi; }
                }
                if (l16 == 0) {
                    int row = tile_m + wm + i * 16 + (quad << 2) + r;
                    u64 key = ((u64)f2ord(best) << 32) | (unsigned)bi;
                    atomicMin(&keys[row], key);
                }
            }
        }
    } else {  // EPI == 3: tanh + SSE vs fp32 action (cols >= AA zero-padded)
        float ls = 0.f;
#pragma unroll
        for (int i = 0; i < 4; i++) {
            int row = tile_m + wm + i * 16 + (quad << 2);
#pragma unroll
            for (int j = 0; j < 4; j++) {
                int col = wn + j * 16 + l16;
                if (col < AA) {
                    float bv = bias[col];
#pragma unroll
                    for (int r = 0; r < 4; r++) {
                        float v = tanhf(__builtin_fmaf(acc[i][j][r], ds, bv));
                        float d = v - actionf[(long)(row + r) * AA + col];
                        ls += d * d;
                    }
                }
            }
        }
#pragma unroll
        for (int off = 32; off; off >>= 1) ls += __shfl_down(ls, off);
        __shared__ float wsum[4];
        if (lane == 0) wsum[wave] = ls;
        __syncthreads();
        if (t == 0) atomicAdd(&partials[64 + (blockIdx.y & 63)], wsum[0] + wsum[1] + wsum[2] + wsum[3]);
    }
}

// ---------------------------------------------------------------------------
// Gather q = codebook[idx] -> qb (MX fragment-major fp8 x1024, KST=2) and
// SSE(q - enc) from MX fragment-major enc8 (/16) -> partials[0..63]
// ---------------------------------------------------------------------------
__global__ void gather_vq(const u64* __restrict__ keys, const float* __restrict__ cb,
                          const u8* __restrict__ enc8, u8* __restrict__ q8,
                          float* __restrict__ partials)
{
    const int t = threadIdx.x;
    float s = 0.f;
#pragma unroll
    for (int e = 0; e < 4; e++) {
        int g = blockIdx.x * 1024 + e * 256 + t;    // u64-group index
        int gl = g & 255;
        int lane = gl >> 2, w = gl & 3;
        int F = g >> 8;
        int S = F & 1, R = F >> 1;                  // KST = 2
        int b = R * 16 + (lane & 15);
        int d0 = S * 128 + ((lane >> 4) << 5) + (w << 3);
        int code = (int)(keys[b] & 0xFFFFFFFFull);
        const float* crow = cb + (long)code * DD + d0;
        u64 enc = ((const u64*)enc8)[g];
        u64 wv = 0;
#pragma unroll
        for (int j = 0; j < 8; j++) {
            float qv = crow[j];
            wv |= (u64)f2f8(qv * 1024.f) << (8 * j);
            float ev = f8tof((u8)(enc >> (8 * j))) * 0.0625f;
            float df = qv - ev;
            s += df * df;
        }
        ((u64*)q8)[g] = wv;
    }
#pragma unroll
    for (int off = 32; off; off >>= 1) s += __shfl_down(s, off);
    __shared__ float wsum[4];
    int wave = t >> 6, lane = t & 63;
    if (lane == 0) wsum[wave] = s;
    __syncthreads();
    if (t == 0) atomicAdd(&partials[blockIdx.x & 63], wsum[0] + wsum[1] + wsum[2] + wsum[3]);
}

__global__ void finalize_kernel(const float* __restrict__ partials, float* __restrict__ out)
{
    int t = threadIdx.x;  // 64 threads
    float v = partials[t];
    float r = partials[64 + t];
#pragma unroll
    for (int off = 32; off; off >>= 1) { v += __shfl_down(v, off); r += __shfl_down(r, off); }
    if (t == 0) {
        float m = v * (1.f / ((float)BB * (float)DD));   // commitment == embedding (fwd)
        float vql = 1.25f * m;                           // 0.25*m + m
        float rl = r * (1.f / ((float)BB * (float)AA));
        out[0] = rl + vql;
        out[1] = rl;
        out[2] = vql;
        out[3] = m;
        out[4] = m;
    }
}

extern "C" void kernel_launch(void* const* d_in, const int* in_sizes, int n_in,
                              void* d_out, int out_size, void* d_ws, size_t ws_size,
                              hipStream_t stream)
{
    (void)in_sizes; (void)n_in; (void)out_size; (void)ws_size;
    const float* action   = (const float*)d_in[0];
    const float* enc_w1   = (const float*)d_in[1];
    const float* enc_b1   = (const float*)d_in[2];
    const float* enc_w2   = (const float*)d_in[3];
    const float* enc_b2   = (const float*)d_in[4];
    const float* mu_w     = (const float*)d_in[5];
    const float* mu_b     = (const float*)d_in[6];
    const float* codebook = (const float*)d_in[7];
    const float* dec_w1   = (const float*)d_in[8];
    const float* dec_b1   = (const float*)d_in[9];
    const float* dec_w2   = (const float*)d_in[10];
    const float* dec_b2   = (const float*)d_in[11];
    const float* dec_w3   = (const float*)d_in[12];
    const float* dec_b3   = (const float*)d_in[13];

    char* ws = (char*)d_ws;
    size_t off = 0;
    auto alloc = [&](size_t bytes) { char* p = ws + off; off += (bytes + 255) & ~(size_t)255; return p; };
    u8* af8      = (u8*)alloc((size_t)BB * 128);       // 4 MB (K padded 64->128)
    u8* ew1t     = (u8*)alloc((size_t)HH * 128);       // 128 KB
    u8* ew2t     = (u8*)alloc((size_t)HH * HH);        // 1 MB
    u8* muwt     = (u8*)alloc((size_t)DD * HH);        // 256 KB
    u8* cbf8     = (u8*)alloc((size_t)KK * DD);        // 1 MB
    u8* dw1t     = (u8*)alloc((size_t)HH * DD);        // 256 KB
    u8* dw2t     = (u8*)alloc((size_t)HH * HH);        // 1 MB
    u8* dw3t     = (u8*)alloc((size_t)128 * HH);       // 128 KB
    float* cnorm = (float*)alloc((size_t)KK * 4);
    u64* keys    = (u64*)alloc((size_t)BB * 8);        // 256 KB
    float* partials = (float*)alloc(128 * 4);
    u8* h1       = (u8*)alloc((size_t)BB * HH);        // 32 MB
    u8* h2       = (u8*)alloc((size_t)BB * HH);        // 32 MB
    u8* encb     = (u8*)alloc((size_t)BB * DD);        // 8 MB
    u8* qb       = (u8*)alloc((size_t)BB * DD);        // 8 MB

    hipMemsetAsync(keys, 0xFF, (size_t)BB * 8, stream);
    hipMemsetAsync(partials, 0, 128 * 4, stream);

    prep_kernel<<<2016, 256, 0, stream>>>(action, enc_w1, enc_w2, mu_w, codebook,
                                          dec_w1, dec_w2, dec_w3,
                                          af8, ew1t, ew2t, muwt, cbf8, dw1t, dw2t, dw3t, cnorm);

    // encoder  (ds = 1/(scaleA*scaleB), os = activation store scale 16)
    gemm_mx<HH, 128, 0><<<dim3(HH / 128, BB / 128), 256, 0, stream>>>(
        af8, ew1t, enc_b1, h1, 1.f / 512.f, 16.f, nullptr, nullptr, nullptr, nullptr);
    gemm_mx<HH, HH, 0><<<dim3(HH / 128, BB / 128), 256, 0, stream>>>(
        h1, ew2t, enc_b2, h2, 1.f / 1024.f, 16.f, nullptr, nullptr, nullptr, nullptr);
    gemm_mx<DD, HH, 1><<<dim3(DD / 128, BB / 128), 256, 0, stream>>>(
        h2, muwt, mu_b, encb, 1.f / 1024.f, 16.f, nullptr, nullptr, nullptr, nullptr);
    // VQ: argmin over codebook of cnorm[k] - 2*enc.c_k   (ds = 1/(16*1024))
    gemm_mx<KK, DD, 2><<<dim3(KK / 128, BB / 128), 256, 0, stream>>>(
        encb, cbf8, nullptr, nullptr, 1.f / 16384.f, 0.f, cnorm, keys, nullptr, nullptr);
    gather_vq<<<(BB * DD) / 8192, 256, 0, stream>>>(keys, codebook, encb, qb, partials);
    // decoder
    gemm_mx<HH, DD, 0><<<dim3(HH / 128, BB / 128), 256, 0, stream>>>(
        qb, dw1t, dec_b1, h1, 1.f / 65536.f, 16.f, nullptr, nullptr, nullptr, nullptr);
    gemm_mx<HH, HH, 0><<<dim3(HH / 128, BB / 128), 256, 0, stream>>>(
        h1, dw2t, dec_b2, h2, 1.f / 1024.f, 16.f, nullptr, nullptr, nullptr, nullptr);
    gemm_mx<128, HH, 3><<<dim3(1, BB / 128), 256, 0, stream>>>(
        h2, dw3t, dec_b3, nullptr, 1.f / 1024.f, 0.f, nullptr, nullptr, action, partials);

    finalize_kernel<<<1, 64, 0, stream>>>(partials, (float*)d_out);
}

// Round 9
// 550.528 us; speedup vs baseline: 1.0745x; 1.0745x over previous
//
#include <hip/hip_runtime.h>
#include <hip/hip_bf16.h>
#include <hip/hip_fp8.h>

#define BB 32768
#define AA 64
#define HH 1024
#define DD 256
#define KK 4096

typedef __attribute__((ext_vector_type(4))) float f32x4;
typedef unsigned long long u64;
typedef unsigned char u8;
typedef unsigned int u32;

__device__ __forceinline__ u8 f2f8(float x) { __hip_fp8_e4m3 v(x); return (u8)v.__x; }
__device__ __forceinline__ float f8tof(u8 b) { __hip_fp8_e4m3 t; t.__x = (__hip_fp8_storage_t)b; return (float)t; }
__device__ __forceinline__ unsigned f2ord(float f) {
    unsigned u = __float_as_uint(f);
    return (u & 0x80000000u) ? ~u : (u | 0x80000000u);
}

// ---------------------------------------------------------------------------
// Fragment-major layout for an operand X[rows x K] consumed by 16x16x32 MFMA:
//   fragment (R = row/16, S = k/32) = 512 B at ((R*KS + S)*64 + lane)*8,
//   lane = (row%16) | ((k%32)/8)<<4, byte j = k%8.   KS = K/32.
// A wave loads one fragment with ONE 8-B/lane load = 512 contiguous bytes.
// Scales: action x8, weights x64, activations x16, codebook & q x1024.
// ---------------------------------------------------------------------------

// Prep: pack all operands into fragment-major fp8.  Each section: thread
// handles 4 8-byte groups (coalesced u64 stores), strided reads from fp32.
__global__ void prep_kernel(const float* __restrict__ action,
                            const float* __restrict__ enc_w1,
                            const float* __restrict__ enc_w2,
                            const float* __restrict__ mu_w,
                            const float* __restrict__ codebook,
                            const float* __restrict__ dec_w1,
                            const float* __restrict__ dec_w2,
                            const float* __restrict__ dec_w3,
                            u8* __restrict__ af8, u8* __restrict__ ew1t,
                            u8* __restrict__ ew2t, u8* __restrict__ muwt,
                            u8* __restrict__ cbf8, u8* __restrict__ dw1t,
                            u8* __restrict__ dw2t, u8* __restrict__ dw3t,
                            float* __restrict__ cnorm)
{
    int blk = blockIdx.x;
    const int t = threadIdx.x;

#define PACK_SECTION(NBLK, LOG2KS, DST, READER)                                \
    if (blk < (NBLK)) {                                                        \
        _Pragma("unroll")                                                      \
        for (int i = 0; i < 4; i++) {                                          \
            int g = blk * 1024 + i * 256 + t;                                  \
            int lane = g & 63;                                                 \
            int F = g >> 6;                                                    \
            int S = F & ((1 << (LOG2KS)) - 1);                                 \
            int R = F >> (LOG2KS);                                             \
            int n = R * 16 + (lane & 15);                                      \
            int k0 = S * 32 + ((lane >> 4) << 3);                              \
            u64 w = 0;                                                         \
            _Pragma("unroll")                                                  \
            for (int j = 0; j < 8; j++) {                                      \
                int k = k0 + j;                                                \
                float val = (READER);                                          \
                w |= (u64)f2f8(val) << (8 * j);                                \
            }                                                                  \
            ((u64*)(DST))[g] = w;                                              \
        }                                                                      \
        return;                                                                \
    }                                                                          \
    blk -= (NBLK);

    // action [32768x64] -> af8 [rows=32768, K=128 padded], x8
    PACK_SECTION(512, 2, af8, (k < AA ? action[n * AA + k] * 8.f : 0.f))
    // enc_w1 (64,1024) -> ew1t [rows=1024, K=128 padded], x64
    PACK_SECTION(16, 2, ew1t, (k < AA ? enc_w1[k * HH + n] * 64.f : 0.f))
    // enc_w2 (1024,1024) -> ew2t [1024, K=1024], x64
    PACK_SECTION(128, 5, ew2t, (enc_w2[k * HH + n] * 64.f))
    // mu_w (1024,256) -> muwt [256, K=1024], x64
    PACK_SECTION(32, 5, muwt, (mu_w[k * DD + n] * 64.f))
    // codebook [4096x256] -> cbf8 [4096, K=256], x1024
    PACK_SECTION(128, 3, cbf8, (codebook[n * DD + k] * 1024.f))
    // dec_w1 (256,1024) -> dw1t [1024, K=256], x64
    PACK_SECTION(32, 3, dw1t, (dec_w1[k * HH + n] * 64.f))
    // dec_w2 (1024,1024) -> dw2t [1024, K=1024], x64
    PACK_SECTION(128, 5, dw2t, (dec_w2[k * HH + n] * 64.f))
    // dec_w3 (1024,64) -> dw3t [rows=128 padded, K=1024], x64
    PACK_SECTION(16, 5, dw3t, (n < AA ? dec_w3[k * AA + n] * 64.f : 0.f))
#undef PACK_SECTION

    {   // cnorm: 4 rows/block, wave per row, fp32 exact
        int wave = t >> 6, lane = t & 63;
        int row = blk * 4 + wave;
        const float4* cr = (const float4*)(codebook + (long)row * DD);
        float4 v = cr[lane];
        float s = v.x * v.x + v.y * v.y + v.z * v.z + v.w * v.w;
#pragma unroll
        for (int off = 32; off; off >>= 1) s += __shfl_down(s, off);
        if (lane == 0) cnorm[row] = s;
    }
}

// ---------------------------------------------------------------------------
// Barrier-free fp8 GEMM on fragment-major operands, SOFTWARE-PIPELINED.
// 128x128 tile, 4 waves (2x2 of 64x64), 16x16x32 fp8_fp8 MFMA.  Per K-step:
// 8 fully-coalesced 512-B fragment loads (global->VGPR) + 16 MFMAs.  No LDS
// and no __syncthreads in the K-loop; fragments of iter s+1 are prefetched
// into a second register set before iter s's MFMAs so load latency overlaps
// compute.  __launch_bounds__(256,3) (~170 regs) gives the allocator room
// (R7's 128-reg cap starved the pipeline -> serialized load->wait->MFMA).
// EPI 0/1: (relu)(v*ds+bias)*os -> C fragment-major via LDS transpose
// EPI 2:   VQ argmin (cnorm - 2v*ds -> u64 atomicMin keys)
// EPI 3:   tanh(v*ds+bias), SSE vs fp32 action -> partials[64+..]
// ---------------------------------------------------------------------------
template <int N, int K, int EPI>
__global__ __launch_bounds__(256, 3) void gemm_f8(
    const u8* __restrict__ A, const u8* __restrict__ Bt,
    const float* __restrict__ bias, u8* __restrict__ C,
    float ds, float os,
    const float* __restrict__ cnorm, u64* __restrict__ keys,
    const float* __restrict__ actionf, float* __restrict__ partials)
{
    constexpr int KS = K / 32;
    constexpr int KSo = N / 32;
    __shared__ __align__(16) u8 ctile[128 * 132];   // epilogue only
    const int t = threadIdx.x;
    const int wave = t >> 6, lane = t & 63;
    const int quad = lane >> 4, l16 = lane & 15;
    const int wm = (wave >> 1) << 6, wn = (wave & 1) << 6;
    const int tile_m = blockIdx.y << 7;
    const int tile_n = blockIdx.x << 7;

    const u8* pa = A + ((long)((tile_m + wm) >> 4) * KS) * 512 + lane * 8;
    const u8* pb = Bt + ((long)((tile_n + wn) >> 4) * KS) * 512 + lane * 8;

    f32x4 acc[4][4];
#pragma unroll
    for (int i = 0; i < 4; i++)
#pragma unroll
        for (int j = 0; j < 4; j++) acc[i][j] = (f32x4){0.f, 0.f, 0.f, 0.f};

    long a_[4], b_[4], an[4], bn[4];
#pragma unroll
    for (int i = 0; i < 4; i++) a_[i] = *(const long*)(pa + (i * KS) * 512);
#pragma unroll
    for (int j = 0; j < 4; j++) b_[j] = *(const long*)(pb + (j * KS) * 512);

#pragma unroll
    for (int s = 0; s < KS; s++) {
        if (s + 1 < KS) {
#pragma unroll
            for (int i = 0; i < 4; i++) an[i] = *(const long*)(pa + (i * KS + s + 1) * 512);
#pragma unroll
            for (int j = 0; j < 4; j++) bn[j] = *(const long*)(pb + (j * KS + s + 1) * 512);
        }
#pragma unroll
        for (int i = 0; i < 4; i++)
#pragma unroll
            for (int j = 0; j < 4; j++)
                acc[i][j] = __builtin_amdgcn_mfma_f32_16x16x32_fp8_fp8(a_[i], b_[j], acc[i][j], 0, 0, 0);
#pragma unroll
        for (int i = 0; i < 4; i++) { a_[i] = an[i]; b_[i] = bn[i]; }
    }

    // C/D layout: col = lane&15, row = quad*4 + reg
    if (EPI == 0 || EPI == 1) {
#pragma unroll
        for (int i = 0; i < 4; i++) {
#pragma unroll
            for (int j = 0; j < 4; j++) {
                int col = wn + j * 16 + l16;
                float bv = bias[tile_n + col];
#pragma unroll
                for (int r = 0; r < 4; r++) {
                    float v = __builtin_fmaf(acc[i][j][r], ds, bv);
                    if (EPI == 0) v = fmaxf(v, 0.f);
                    ctile[(wm + i * 16 + (quad << 2) + r) * 132 + col] = f2f8(v * os);
                }
            }
        }
        __syncthreads();
        // read back in fragment order, store coalesced u64 per fragment
#pragma unroll
        for (int ff = 0; ff < 8; ff++) {
            int f = wave * 8 + ff;
            int Rl = f >> 2, Sl = f & 3;
            int a = (Rl * 16 + l16) * 132 + Sl * 32 + (quad << 3);
            u32 lo = *(const u32*)&ctile[a];
            u32 hi = *(const u32*)&ctile[a + 4];
            long Rg = (tile_m >> 4) + Rl;
            int Sg = (tile_n >> 5) + Sl;
            *(uint2*)(C + ((Rg * KSo + Sg) * 64 + lane) * 8) = make_uint2(lo, hi);
        }
    } else if (EPI == 2) {
#pragma unroll
        for (int i = 0; i < 4; i++) {
#pragma unroll
            for (int r = 0; r < 4; r++) {
                float best = 3.4e38f; int bi = 0;
#pragma unroll
                for (int j = 0; j < 4; j++) {
                    int col = tile_n + wn + j * 16 + l16;
                    float v = __builtin_fmaf(-2.f * ds, acc[i][j][r], cnorm[col]);
                    if (v < best || (v == best && col < bi)) { best = v; bi = col; }
                }
#pragma unroll
                for (int off = 1; off < 16; off <<= 1) {
                    float ov = __shfl_xor(best, off);
                    int   oi = __shfl_xor(bi, off);
                    if (ov < best || (ov == best && oi < bi)) { best = ov; bi = oi; }
                }
                if (l16 == 0) {
                    int row = tile_m + wm + i * 16 + (quad << 2) + r;
                    u64 key = ((u64)f2ord(best) << 32) | (unsigned)bi;
                    atomicMin(&keys[row], key);
                }
            }
        }
    } else {  // EPI == 3: tanh + SSE vs fp32 action (cols >= AA zero-padded)
        float ls = 0.f;
#pragma unroll
        for (int i = 0; i < 4; i++) {
            int row = tile_m + wm + i * 16 + (quad << 2);
#pragma unroll
            for (int j = 0; j < 4; j++) {
                int col = wn + j * 16 + l16;
                if (col < AA) {
                    float bv = bias[col];
#pragma unroll
                    for (int r = 0; r < 4; r++) {
                        float v = tanhf(__builtin_fmaf(acc[i][j][r], ds, bv));
                        float d = v - actionf[(long)(row + r) * AA + col];
                        ls += d * d;
                    }
                }
            }
        }
#pragma unroll
        for (int off = 32; off; off >>= 1) ls += __shfl_down(ls, off);
        __shared__ float wsum[4];
        if (lane == 0) wsum[wave] = ls;
        __syncthreads();
        if (t == 0) atomicAdd(&partials[64 + (blockIdx.y & 63)], wsum[0] + wsum[1] + wsum[2] + wsum[3]);
    }
}

// ---------------------------------------------------------------------------
// Gather q = codebook[idx] -> qb (fragment-major fp8 x1024, KS=8) and
// SSE(q - enc) from fragment-major enc8 (/16) -> partials[0..63]
// ---------------------------------------------------------------------------
__global__ void gather_vq(const u64* __restrict__ keys, const float* __restrict__ cb,
                          const u8* __restrict__ enc8, u8* __restrict__ q8,
                          float* __restrict__ partials)
{
    const int t = threadIdx.x;
    float s = 0.f;
#pragma unroll
    for (int e = 0; e < 4; e++) {
        int g = blockIdx.x * 1024 + e * 256 + t;    // 8-byte group index
        int lane = g & 63;
        int F = g >> 6;
        int S = F & 7, R = F >> 3;
        int b = R * 16 + (lane & 15);
        int d0 = S * 32 + ((lane >> 4) << 3);
        int code = (int)(keys[b] & 0xFFFFFFFFull);
        const float* crow = cb + (long)code * DD + d0;
        u64 enc = ((const u64*)enc8)[g];
        u64 w = 0;
#pragma unroll
        for (int j = 0; j < 8; j++) {
            float qv = crow[j];
            w |= (u64)f2f8(qv * 1024.f) << (8 * j);
            float ev = f8tof((u8)(enc >> (8 * j))) * 0.0625f;
            float df = qv - ev;
            s += df * df;
        }
        ((u64*)q8)[g] = w;
    }
#pragma unroll
    for (int off = 32; off; off >>= 1) s += __shfl_down(s, off);
    __shared__ float wsum[4];
    int wave = t >> 6, lane = t & 63;
    if (lane == 0) wsum[wave] = s;
    __syncthreads();
    if (t == 0) atomicAdd(&partials[blockIdx.x & 63], wsum[0] + wsum[1] + wsum[2] + wsum[3]);
}

__global__ void finalize_kernel(const float* __restrict__ partials, float* __restrict__ out)
{
    int t = threadIdx.x;  // 64 threads
    float v = partials[t];
    float r = partials[64 + t];
#pragma unroll
    for (int off = 32; off; off >>= 1) { v += __shfl_down(v, off); r += __shfl_down(r, off); }
    if (t == 0) {
        float m = v * (1.f / ((float)BB * (float)DD));   // commitment == embedding (fwd)
        float vql = 1.25f * m;                           // 0.25*m + m
        float rl = r * (1.f / ((float)BB * (float)AA));
        out[0] = rl + vql;
        out[1] = rl;
        out[2] = vql;
        out[3] = m;
        out[4] = m;
    }
}

extern "C" void kernel_launch(void* const* d_in, const int* in_sizes, int n_in,
                              void* d_out, int out_size, void* d_ws, size_t ws_size,
                              hipStream_t stream)
{
    (void)in_sizes; (void)n_in; (void)out_size; (void)ws_size;
    const float* action   = (const float*)d_in[0];
    const float* enc_w1   = (const float*)d_in[1];
    const float* enc_b1   = (const float*)d_in[2];
    const float* enc_w2   = (const float*)d_in[3];
    const float* enc_b2   = (const float*)d_in[4];
    const float* mu_w     = (const float*)d_in[5];
    const float* mu_b     = (const float*)d_in[6];
    const float* codebook = (const float*)d_in[7];
    const float* dec_w1   = (const float*)d_in[8];
    const float* dec_b1   = (const float*)d_in[9];
    const float* dec_w2   = (const float*)d_in[10];
    const float* dec_b2   = (const float*)d_in[11];
    const float* dec_w3   = (const float*)d_in[12];
    const float* dec_b3   = (const float*)d_in[13];

    char* ws = (char*)d_ws;
    size_t off = 0;
    auto alloc = [&](size_t bytes) { char* p = ws + off; off += (bytes + 255) & ~(size_t)255; return p; };
    u8* af8      = (u8*)alloc((size_t)BB * 128);       // 4 MB (K padded 64->128)
    u8* ew1t     = (u8*)alloc((size_t)HH * 128);       // 128 KB
    u8* ew2t     = (u8*)alloc((size_t)HH * HH);        // 1 MB
    u8* muwt     = (u8*)alloc((size_t)DD * HH);        // 256 KB
    u8* cbf8     = (u8*)alloc((size_t)KK * DD);        // 1 MB
    u8* dw1t     = (u8*)alloc((size_t)HH * DD);        // 256 KB
    u8* dw2t     = (u8*)alloc((size_t)HH * HH);        // 1 MB
    u8* dw3t     = (u8*)alloc((size_t)128 * HH);       // 128 KB
    float* cnorm = (float*)alloc((size_t)KK * 4);
    u64* keys    = (u64*)alloc((size_t)BB * 8);        // 256 KB
    float* partials = (float*)alloc(128 * 4);
    u8* h1       = (u8*)alloc((size_t)BB * HH);        // 32 MB
    u8* h2       = (u8*)alloc((size_t)BB * HH);        // 32 MB
    u8* encb     = (u8*)alloc((size_t)BB * DD);        // 8 MB
    u8* qb       = (u8*)alloc((size_t)BB * DD);        // 8 MB

    hipMemsetAsync(keys, 0xFF, (size_t)BB * 8, stream);
    hipMemsetAsync(partials, 0, 128 * 4, stream);

    prep_kernel<<<2016, 256, 0, stream>>>(action, enc_w1, enc_w2, mu_w, codebook,
                                          dec_w1, dec_w2, dec_w3,
                                          af8, ew1t, ew2t, muwt, cbf8, dw1t, dw2t, dw3t, cnorm);

    // encoder  (ds = 1/(scaleA*scaleB), os = activation store scale)
    gemm_f8<HH, 128, 0><<<dim3(HH / 128, BB / 128), 256, 0, stream>>>(
        af8, ew1t, enc_b1, h1, 1.f / 512.f, 16.f, nullptr, nullptr, nullptr, nullptr);
    gemm_f8<HH, HH, 0><<<dim3(HH / 128, BB / 128), 256, 0, stream>>>(
        h1, ew2t, enc_b2, h2, 1.f / 1024.f, 16.f, nullptr, nullptr, nullptr, nullptr);
    gemm_f8<DD, HH, 1><<<dim3(DD / 128, BB / 128), 256, 0, stream>>>(
        h2, muwt, mu_b, encb, 1.f / 1024.f, 16.f, nullptr, nullptr, nullptr, nullptr);
    // VQ: argmin over codebook of cnorm[k] - 2*enc.c_k   (ds = 1/(16*1024))
    gemm_f8<KK, DD, 2><<<dim3(KK / 128, BB / 128), 256, 0, stream>>>(
        encb, cbf8, nullptr, nullptr, 1.f / 16384.f, 0.f, cnorm, keys, nullptr, nullptr);
    gather_vq<<<(BB * DD) / 8192, 256, 0, stream>>>(keys, codebook, encb, qb, partials);
    // decoder
    gemm_f8<HH, DD, 0><<<dim3(HH / 128, BB / 128), 256, 0, stream>>>(
        qb, dw1t, dec_b1, h1, 1.f / 65536.f, 16.f, nullptr, nullptr, nullptr, nullptr);
    gemm_f8<HH, HH, 0><<<dim3(HH / 128, BB / 128), 256, 0, stream>>>(
        h1, dw2t, dec_b2, h2, 1.f / 1024.f, 16.f, nullptr, nullptr, nullptr, nullptr);
    gemm_f8<128, HH, 3><<<dim3(1, BB / 128), 256, 0, stream>>>(
        h2, dw3t, dec_b3, nullptr, 1.f / 1024.f, 0.f, nullptr, nullptr, action, partials);

    finalize_kernel<<<1, 64, 0, stream>>>(partials, (float*)d_out);
}